// Round 1
// baseline (576.463 us; speedup 1.0000x reference)
//
#include <hip/hip_runtime.h>
#include <cstddef>
#include <cstdint>

static constexpr int NN   = 50000;   // nodes
static constexpr int NE   = 800000;  // edges (without self loops)
static constexpr int NG   = 256;     // graphs
static constexpr int FIN  = 128;
static constexpr int HID  = 256;
static constexpr int EMB  = 128;
static constexpr int NGRP = 16;
static constexpr int NFAM = 128;

// ---------------- degree / CSR build ----------------

__global__ void k_init_deg(int* __restrict__ degi, int n) {
    int i = blockIdx.x * blockDim.x + threadIdx.x;
    if (i < n) degi[i] = 1;  // self loop
}

__global__ void k_count(const int* __restrict__ edst, int* __restrict__ degi, int e) {
    int i = blockIdx.x * blockDim.x + threadIdx.x;
    if (i < e) atomicAdd(degi + edst[i], 1);
}

__global__ void k_dinv(const int* __restrict__ degi, float* __restrict__ dinv, int n) {
    int i = blockIdx.x * blockDim.x + threadIdx.x;
    if (i < n) dinv[i] = rsqrtf((float)degi[i]);
}

// single-block exclusive scan of (degi[i]-1) -> row_ptr; also zeros cursor
__global__ __launch_bounds__(1024) void k_scan(const int* __restrict__ degi,
                                               int* __restrict__ row_ptr,
                                               int* __restrict__ cursor, int n) {
    __shared__ int ps[1024];
    const int t  = threadIdx.x;
    const int CH = (n + 1023) / 1024;
    int lo = t * CH;
    int hi = min(lo + CH, n);
    int s = 0;
    for (int i = lo; i < hi; ++i) s += degi[i] - 1;
    ps[t] = s;
    __syncthreads();
    for (int off = 1; off < 1024; off <<= 1) {
        int v = (t >= off) ? ps[t - off] : 0;
        __syncthreads();
        if (t >= off) ps[t] += v;
        __syncthreads();
    }
    int run = (t == 0) ? 0 : ps[t - 1];
    for (int i = lo; i < hi; ++i) {
        row_ptr[i] = run;
        cursor[i]  = 0;
        run += degi[i] - 1;
    }
    if (t == 1023) row_ptr[n] = ps[1023];
}

__global__ void k_fill(const int* __restrict__ esrc, const int* __restrict__ edst,
                       const int* __restrict__ row_ptr, int* __restrict__ cursor,
                       int* __restrict__ col, int e) {
    int i = blockIdx.x * blockDim.x + threadIdx.x;
    if (i < e) {
        int d = edst[i];
        int p = atomicAdd(cursor + d, 1);
        col[row_ptr[d] + p] = esrc[i];
    }
}

__global__ void k_gstart(const int* __restrict__ batch, int* __restrict__ gstart,
                         int n, int G) {
    int i = blockIdx.x * blockDim.x + threadIdx.x;
    if (i >= n) return;
    int b  = batch[i];
    int pb = (i == 0) ? -1 : batch[i - 1];
    for (int g = pb + 1; g <= b; ++g) gstart[g] = i;
    if (i == n - 1) {
        for (int g = b + 1; g <= G; ++g) gstart[g] = n;
    }
}

// ---------------- fp32 tiled GEMM: C[m,n] = (A[m,:] @ W[:,n]) * scale[m] ----------------
// BM=BN=BK=64, 256 threads, 4x4 micro-tile per thread.

__global__ __launch_bounds__(256) void k_gemm_scaled(
        const float* __restrict__ A, const float* __restrict__ W,
        const float* __restrict__ scale, float* __restrict__ C,
        int M, int N, int K) {
    __shared__ float As[64][68];
    __shared__ float Ws[64][68];
    const int t  = threadIdx.x;
    const int tx = t & 15;
    const int ty = t >> 4;
    const int m0 = blockIdx.x * 64;
    const int n0 = blockIdx.y * 64;

    float acc[4][4] = {};

    for (int k0 = 0; k0 < K; k0 += 64) {
#pragma unroll
        for (int l = 0; l < 4; ++l) {
            int lin = t + l * 256;          // 0..1023
            int r   = lin >> 4;             // 0..63
            int c4  = (lin & 15) << 2;      // 0..60 step 4
            float4 av = make_float4(0.f, 0.f, 0.f, 0.f);
            int gr = m0 + r;
            if (gr < M) av = *(const float4*)(A + (size_t)gr * K + k0 + c4);
            *(float4*)&As[r][c4] = av;
            float4 wv = *(const float4*)(W + (size_t)(k0 + r) * N + n0 + c4);
            *(float4*)&Ws[r][c4] = wv;
        }
        __syncthreads();
#pragma unroll 8
        for (int kk = 0; kk < 64; ++kk) {
            float a0 = As[ty * 4 + 0][kk];
            float a1 = As[ty * 4 + 1][kk];
            float a2 = As[ty * 4 + 2][kk];
            float a3 = As[ty * 4 + 3][kk];
            float4 b = *(const float4*)&Ws[kk][tx * 4];
            acc[0][0] += a0 * b.x; acc[0][1] += a0 * b.y; acc[0][2] += a0 * b.z; acc[0][3] += a0 * b.w;
            acc[1][0] += a1 * b.x; acc[1][1] += a1 * b.y; acc[1][2] += a1 * b.z; acc[1][3] += a1 * b.w;
            acc[2][0] += a2 * b.x; acc[2][1] += a2 * b.y; acc[2][2] += a2 * b.z; acc[2][3] += a2 * b.w;
            acc[3][0] += a3 * b.x; acc[3][1] += a3 * b.y; acc[3][2] += a3 * b.z; acc[3][3] += a3 * b.w;
        }
        __syncthreads();
    }

#pragma unroll
    for (int i = 0; i < 4; ++i) {
        int gr = m0 + ty * 4 + i;
        if (gr < M) {
            float sc = scale ? scale[gr] : 1.0f;
            float4 o;
            o.x = acc[i][0] * sc;
            o.y = acc[i][1] * sc;
            o.z = acc[i][2] * sc;
            o.w = acc[i][3] * sc;
            *(float4*)(C + (size_t)gr * N + n0 + tx * 4) = o;
        }
    }
}

// ---------------- neighbor aggregation: out[i] = act(dinv[i]*(hw[i] + sum_nbr hw[s]) + b) ----------------

template <int F, bool RELU>
__global__ __launch_bounds__(256) void k_aggregate(
        const float* __restrict__ hw, const int* __restrict__ row_ptr,
        const int* __restrict__ col, const float* __restrict__ dinv,
        const float* __restrict__ bias, float* __restrict__ out, int n) {
    int node = blockIdx.x * 4 + (threadIdx.x >> 6);
    if (node >= n) return;
    int lane = threadIdx.x & 63;
    constexpr int V = F / 64;  // 4 (F=256) or 2 (F=128)
    float acc[V];
    {
        const float* r = hw + (size_t)node * F + lane * V;
        if constexpr (V == 4) {
            float4 v = *(const float4*)r;
            acc[0] = v.x; acc[1] = v.y; acc[2] = v.z; acc[3] = v.w;
        } else {
            float2 v = *(const float2*)r;
            acc[0] = v.x; acc[1] = v.y;
        }
    }
    int beg = row_ptr[node], end = row_ptr[node + 1];
    for (int j = beg; j < end; ++j) {
        int s = col[j];
        const float* r = hw + (size_t)s * F + lane * V;
        if constexpr (V == 4) {
            float4 v = *(const float4*)r;
            acc[0] += v.x; acc[1] += v.y; acc[2] += v.z; acc[3] += v.w;
        } else {
            float2 v = *(const float2*)r;
            acc[0] += v.x; acc[1] += v.y;
        }
    }
    float di = dinv[node];
#pragma unroll
    for (int k = 0; k < V; ++k) {
        float v = di * acc[k] + bias[lane * V + k];
        if (RELU) v = fmaxf(v, 0.f);
        out[(size_t)node * F + lane * V + k] = v;
    }
}

// ---------------- mean pool over sorted batch ----------------

__global__ __launch_bounds__(128) void k_pool(const float* __restrict__ h2,
                                              const int* __restrict__ gstart,
                                              float* __restrict__ emb) {
    int g = blockIdx.x, c = threadIdx.x;
    int s0 = gstart[g], s1 = gstart[g + 1];
    float acc = 0.f;
    for (int i = s0; i < s1; ++i) acc += h2[(size_t)i * EMB + c];
    float cnt = (float)(s1 - s0);
    emb[g * EMB + c] = acc / fmaxf(cnt, 1.f);
}

// ---------------- heads: group logits, argmax route, family logits ----------------

__global__ __launch_bounds__(128) void k_head(const float* __restrict__ emb,
                                              const float* __restrict__ Wg,
                                              const float* __restrict__ bg,
                                              const float* __restrict__ Wf,
                                              const float* __restrict__ bf,
                                              float* __restrict__ out_gl,
                                              float* __restrict__ out_fl) {
    __shared__ float e[EMB];
    __shared__ float gl[NGRP];
    __shared__ int ps;
    int g = blockIdx.x, c = threadIdx.x;
    e[c] = emb[g * EMB + c];
    __syncthreads();
    if (c < NGRP) {
        float a = bg[c];
        for (int d = 0; d < EMB; ++d) a += e[d] * Wg[d * NGRP + c];
        gl[c] = a;
        out_gl[g * NGRP + c] = a;
    }
    __syncthreads();
    if (c == 0) {
        int bi = 0;
        float bv = gl[0];
        for (int t2 = 1; t2 < NGRP; ++t2)
            if (gl[t2] > bv) { bv = gl[t2]; bi = t2; }
        ps = bi;
    }
    __syncthreads();
    int p = ps;
    float a = bf[p * NFAM + c];
    for (int d = 0; d < EMB; ++d) a += e[d] * Wf[((size_t)p * EMB + d) * NFAM + c];
    out_fl[g * NFAM + c] = a;
}

// ---------------- launch ----------------

extern "C" void kernel_launch(void* const* d_in, const int* in_sizes, int n_in,
                              void* d_out, int out_size, void* d_ws, size_t ws_size,
                              hipStream_t stream) {
    const float* x   = (const float*)d_in[0];
    const int*   ei  = (const int*)d_in[1];
    const int*   bat = (const int*)d_in[2];
    const float* W1  = (const float*)d_in[3];
    const float* b1  = (const float*)d_in[4];
    const float* W2  = (const float*)d_in[5];
    const float* b2  = (const float*)d_in[6];
    const float* Wg  = (const float*)d_in[7];
    const float* bg  = (const float*)d_in[8];
    const float* Wf  = (const float*)d_in[9];
    const float* bf  = (const float*)d_in[10];

    float* out     = (float*)d_out;
    float* out_emb = out;                       // 256*128
    float* out_gl  = out + (size_t)NG * EMB;    // 256*16
    float* out_fl  = out_gl + (size_t)NG * NGRP;// 256*128

    char* w = (char*)d_ws;
    auto alloc = [&](size_t bytes) {
        char* p = w;
        w += (bytes + 255) & ~(size_t)255;
        return p;
    };
    int*   degi    = (int*)alloc((size_t)NN * 4);
    float* dinv    = (float*)alloc((size_t)NN * 4);
    int*   row_ptr = (int*)alloc((size_t)(NN + 1) * 4);
    int*   cursor  = (int*)alloc((size_t)NN * 4);
    int*   col     = (int*)alloc((size_t)NE * 4);
    int*   gstart  = (int*)alloc((size_t)(NG + 1) * 4);
    float* hw      = (float*)alloc((size_t)NN * HID * 4);  // layer1 hw' / layer2 hw'
    float* h1      = (float*)alloc((size_t)NN * HID * 4);  // h1, then reused as h2

    const int* esrc = ei;
    const int* edst = ei + NE;

    k_init_deg<<<(NN + 255) / 256, 256, 0, stream>>>(degi, NN);
    k_count<<<(NE + 255) / 256, 256, 0, stream>>>(edst, degi, NE);
    k_dinv<<<(NN + 255) / 256, 256, 0, stream>>>(degi, dinv, NN);
    k_scan<<<1, 1024, 0, stream>>>(degi, row_ptr, cursor, NN);
    k_fill<<<(NE + 255) / 256, 256, 0, stream>>>(esrc, edst, row_ptr, cursor, col, NE);
    k_gstart<<<(NN + 255) / 256, 256, 0, stream>>>(bat, gstart, NN, NG);

    // layer 1: hw = (x @ W1) * dinv ; h1 = relu(dinv * agg + b1)
    {
        dim3 grid((NN + 63) / 64, HID / 64);
        k_gemm_scaled<<<grid, 256, 0, stream>>>(x, W1, dinv, hw, NN, HID, FIN);
        k_aggregate<HID, true><<<(NN + 3) / 4, 256, 0, stream>>>(hw, row_ptr, col, dinv, b1, h1, NN);
    }
    // layer 2: hw2 = (h1 @ W2) * dinv ; h2 = dinv * agg + b2   (h2 overwrites h1 buffer)
    {
        dim3 grid((NN + 63) / 64, EMB / 64);
        k_gemm_scaled<<<grid, 256, 0, stream>>>(h1, W2, dinv, hw, NN, EMB, HID);
        k_aggregate<EMB, false><<<(NN + 3) / 4, 256, 0, stream>>>(hw, row_ptr, col, dinv, b2, h1, NN);
    }

    k_pool<<<NG, 128, 0, stream>>>(h1, gstart, out_emb);
    k_head<<<NG, 128, 0, stream>>>(out_emb, Wg, bg, Wf, bf, out_gl, out_fl);
}